// Round 5
// baseline (1235.482 us; speedup 1.0000x reference)
//
#include <hip/hip_runtime.h>

// ---- types ----
typedef __bf16 bf16x8 __attribute__((ext_vector_type(8)));
typedef float  floatx4 __attribute__((ext_vector_type(4)));
typedef float  fvec4  __attribute__((ext_vector_type(4)));
typedef unsigned short ushort4v __attribute__((ext_vector_type(4)));
typedef unsigned short ushort8v __attribute__((ext_vector_type(8)));

__device__ __forceinline__ unsigned short f2bf(float f) {
  unsigned int u = __float_as_uint(f);
  u = u + 0x7FFFu + ((u >> 16) & 1u);   // RNE
  return (unsigned short)(u >> 16);
}

// ws layout:
//   ushort elems: WP2 @0 (29*256*512=3801088), WP3 @3801088 (2*256*768=393216),
//   X0 @4194304 (16*256*128), then pitched per-layer bf16 activations (+64 slack each).
//   byte 64MiB : Y fp32 [31][16*256][128] compact stripe values (65MB).
//   byte 192MiB: barrier counters (32 one-shot) + init flag (word 32).
#define WP3_OFF   3801088
#define X0_OFF    4194304
#define Y_OFF_B   (64u << 20)
#define BAR_OFF_B (192u << 20)
#define INIT_MAGIC 0x13579BDFu

union SMem {
  unsigned short la[32 * 776];        // conv staging, max pitch (KW=3): 49,664 B
  float as[32 * 132];                 // assemble: 31 layers + diag, pitch 132: 16,896 B
};

// ---- device-scope one-shot grid barrier (counters pre-zeroed by wg0 handshake) ----
__device__ __forceinline__ void gbar(unsigned* __restrict__ bar, int idx) {
  __syncthreads();                     // WG stores complete (vmcnt drained -> L2)
  if (threadIdx.x == 0) {
    __threadfence();                   // agent release: publish XCD L2 to LLC
    __hip_atomic_fetch_add(&bar[idx], 1u, __ATOMIC_RELAXED, __HIP_MEMORY_SCOPE_AGENT);
    long t = 0;
    while (__hip_atomic_load(&bar[idx], __ATOMIC_RELAXED, __HIP_MEMORY_SCOPE_AGENT) < 256u) {
      __builtin_amdgcn_s_sleep(1);
      if (++t > (1L << 28)) break;     // bounded: corrupt instead of hang
    }
    __threadfence();                   // agent acquire: invalidate stale lines
  }
  __syncthreads();
}

// ---- conv tile (one 32x64 output tile), verbatim round-3 math ----
template<int KW>
__device__ __forceinline__ void conv_tile(
    unsigned short* __restrict__ LA,
    const unsigned short* __restrict__ Xin, unsigned short* __restrict__ Xout,
    const unsigned short* __restrict__ WP, const float* __restrict__ bias,
    float* __restrict__ Yl,
    int Lpin, int Lout, int Lpout, int b, int m0, int n0, int tid)
{
  constexpr int CS    = (KW == 3) ? 2 : 1;
  constexpr int KS    = 256 * KW;
  constexpr int pitch = KS + 8;
  constexpr int NV    = (KW == 2) ? 5 : 9;

  // stage A tile (vectorized row loads; tail garbage only feeds m>=Lout)
  {
    const int i = tid;
    const unsigned short* rp = Xin + ((b * 256 + i) * Lpin) + CS * m0;
    ushort8v xr[NV];
#pragma unroll
    for (int v = 0; v < NV; ++v)
      xr[v] = *reinterpret_cast<const ushort8v*>(rp + v * 8);
    const unsigned short* xs = reinterpret_cast<const unsigned short*>(xr);
    if (KW == 2) {
#pragma unroll
      for (int m = 0; m < 32; ++m) {
        unsigned int pk = (unsigned int)xs[m] | ((unsigned int)xs[m + 1] << 16);
        *reinterpret_cast<unsigned int*>(&LA[m * pitch + 2 * i]) = pk;
      }
    } else {
#pragma unroll
      for (int m = 0; m < 32; ++m) {
        int base = m * pitch + 3 * i;
        LA[base]     = xs[2 * m];
        LA[base + 1] = xs[2 * m + 1];
        LA[base + 2] = xs[2 * m + 2];
      }
    }
  }
  __syncthreads();

  const int wave = tid >> 6, lane = tid & 63;
  const int l15 = lane & 15, quad = lane >> 4;
  const int nn = n0 + wave * 16 + l15;
  const unsigned short* wrow = WP + (long)nn * KS;
  const int kbase = quad * 8;

  floatx4 acc0 = {0.f, 0.f, 0.f, 0.f};
  floatx4 acc1 = {0.f, 0.f, 0.f, 0.f};

  constexpr int niter = KS / 32;
#pragma unroll
  for (int kc = 0; kc < niter; ++kc) {
    int ko = kc * 32 + kbase;
    bf16x8 bfrag = *reinterpret_cast<const bf16x8*>(wrow + ko);
    bf16x8 a0 = *reinterpret_cast<const bf16x8*>(&LA[l15 * pitch + ko]);
    bf16x8 a1 = *reinterpret_cast<const bf16x8*>(&LA[(16 + l15) * pitch + ko]);
    acc0 = __builtin_amdgcn_mfma_f32_16x16x32_bf16(a0, bfrag, acc0, 0, 0, 0);
    acc1 = __builtin_amdgcn_mfma_f32_16x16x32_bf16(a1, bfrag, acc1, 0, 0, 0);
  }

  const float bv = bias[nn];
  const int row = b * 256 + nn;
  unsigned short* xo = Xout + row * Lpout;
  float* yo = Yl + row * 128;
#pragma unroll
  for (int r = 0; r < 4; ++r) {
    int m = m0 + quad * 4 + r;
    if (m < Lout) {
      float v = acc0[r] + bv;
      xo[m] = f2bf(v);
      yo[m] = v;
    }
    int m2 = m0 + 16 + quad * 4 + r;
    if (m2 < Lout) {
      float v = acc1[r] + bv;
      xo[m2] = f2bf(v);
      yo[m2] = v;
    }
  }
}

// ---- the whole problem in one (plain-launched) kernel with manual grid barriers ----
__launch_bounds__(256)
__global__ void mega_kernel(
    const float* __restrict__ x,
    const float* __restrict__ w2, const float* __restrict__ b2,
    const float* __restrict__ w3, const float* __restrict__ b3,
    float* __restrict__ out, unsigned short* __restrict__ ws,
    float* __restrict__ Y, unsigned* __restrict__ bar)
{
  __shared__ SMem sm;

  const int tid = threadIdx.x;
  const int wg  = blockIdx.x;            // 0..255
  const int gt  = wg * 256 + tid;        // 0..65535

  // ---- init handshake: wg0 zeroes the 32 counters, then raises the flag ----
  if (tid == 0) {
    if (wg == 0) {
      for (int i = 0; i < 32; ++i)
        __hip_atomic_store(&bar[i], 0u, __ATOMIC_RELAXED, __HIP_MEMORY_SCOPE_AGENT);
      __hip_atomic_store(&bar[32], INIT_MAGIC, __ATOMIC_RELEASE, __HIP_MEMORY_SCOPE_AGENT);
    } else {
      long t = 0;
      while (__hip_atomic_load(&bar[32], __ATOMIC_RELAXED, __HIP_MEMORY_SCOPE_AGENT) != INIT_MAGIC) {
        __builtin_amdgcn_s_sleep(1);
        if (++t > (1L << 28)) break;
      }
      __threadfence();
    }
  }
  __syncthreads();

  // ---- phase 0: prep fp32 -> bf16 (w2, w3, x0); 18*65536 = 1,179,648 groups exactly
  for (int it = 0; it < 18; ++it) {
    int g = gt + it * 65536;
    const float* src; unsigned short* dst;
    if (g < 950272)              { src = w2; dst = ws; }
    else if (g < 950272 + 98304) { g -= 950272; src = w3; dst = ws + WP3_OFF; }
    else                         { g -= (950272 + 98304); src = x; dst = ws + X0_OFF; }
    fvec4 v = *reinterpret_cast<const fvec4*>(src + 4 * g);
    ushort4v o;
    o[0] = f2bf(v[0]); o[1] = f2bf(v[1]); o[2] = f2bf(v[2]); o[3] = f2bf(v[3]);
    *reinterpret_cast<ushort4v*>(dst + 4 * g) = o;
  }
  gbar(bar, 0);
  if (wg == 0 && tid == 0)   // all WGs are past init; make flag reentrant-safe
    __hip_atomic_store(&bar[32], 0u, __ATOMIC_RELAXED, __HIP_MEMORY_SCOPE_AGENT);

  // ---- phase 1: 31 conv layers with a grid barrier after each
  {
    int Lin = 128, Lpin = 128, c2 = 0, c3 = 0, lidx = 0;
    long xprev = X0_OFF;
    long xnext = X0_OFF + (long)16 * 256 * 128 + 64;
    for (int ci = 0; ci < 3; ++ci) {
      int cnt = (ci == 0) ? 15 : 8;
      for (int kk = 0; kk < cnt; ++kk) {
        int KW = (ci > 0 && kk == 0) ? 3 : 2;
        int CS = (KW == 3) ? 2 : 1;
        int Lout = (Lin - KW) / CS + 1;
        int Lpout = (Lout + 7) & ~7;
        const unsigned short* WPt;
        const float* bt;
        if (KW == 2) { WPt = ws + (long)c2 * 131072; bt = b2 + c2 * 256; ++c2; }
        else         { WPt = ws + WP3_OFF + (long)c3 * 196608; bt = b3 + c3 * 256; ++c3; }
        int MT = (Lout + 31) >> 5;
        int T  = MT * 64;                 // MT * 4 (n-tiles) * 16 (batch)
        if (wg < T) {
          int mt = wg % MT;
          int nt = (wg / MT) & 3;
          int b  = wg / (MT * 4);
          if (KW == 2)
            conv_tile<2>(sm.la, ws + xprev, ws + xnext, WPt, bt,
                         Y + (long)lidx * 524288, Lpin, Lout, Lpout,
                         b, mt * 32, nt * 64, tid);
          else
            conv_tile<3>(sm.la, ws + xprev, ws + xnext, WPt, bt,
                         Y + (long)lidx * 524288, Lpin, Lout, Lpout,
                         b, mt * 32, nt * 64, tid);
        }
        gbar(bar, 1 + lidx);
        ++lidx;
        xprev = xnext;
        xnext += (long)16 * 256 * Lpout + 64;
        Lin = Lout; Lpin = Lpout;
      }
    }
  }

  // ---- phase 2: assemble — one (b,ch) slice per WG iteration, LDS gather
  // validity: d=c-r: 0 -> diag; 1..15 -> layer d-1 (m=r); 17..31 odd & r even ->
  // layer 15+(d-17)/2 (m=r/2); 35..63 =3 mod 4 & r%4==0 -> layer 23+(d-35)/4 (m=r/4).
  for (int q = 0; q < 16; ++q) {
    int bch = wg * 16 + q;
    __syncthreads();                     // previous iteration's LDS reads done
    if (tid < 248) {                     // stage 31 Y rows (coalesced 512B bursts)
      int l = tid >> 3, s = tid & 7;
      const float* yr = Y + (long)l * 524288 + bch * 128 + s * 16;
      float* dl = sm.as + l * 132 + s * 16;
#pragma unroll
      for (int v = 0; v < 4; ++v)
        *reinterpret_cast<fvec4*>(dl + 4 * v) = *reinterpret_cast<const fvec4*>(yr + 4 * v);
    } else {                             // stage diag row from x
      int s = tid - 248;
      const float* xr = x + bch * 128 + s * 16;
      float* dl = sm.as + 31 * 132 + s * 16;
#pragma unroll
      for (int v = 0; v < 4; ++v)
        *reinterpret_cast<fvec4*>(dl + 4 * v) = *reinterpret_cast<const fvec4*>(xr + 4 * v);
    }
    __syncthreads();
    long obase = (long)bch * 16384;
    for (int u = 0; u < 16; ++u) {
      int z = u * 256 + tid;             // 0..4095
      int r = z >> 5, c4 = z & 31;
      fvec4 v;
#pragma unroll
      for (int jj = 0; jj < 4; ++jj) {
        int c = 4 * c4 + jj;
        int d = c - r;
        float val = 0.f;
        if (d == 0) val = sm.as[31 * 132 + r];
        else if (d >= 1 && d <= 15) val = sm.as[(d - 1) * 132 + r];
        else if (d >= 17 && d <= 31 && (d & 1) == 1 && (r & 1) == 0)
          val = sm.as[(15 + ((d - 17) >> 1)) * 132 + (r >> 1)];
        else if (d >= 35 && d <= 63 && (d & 3) == 3 && (r & 3) == 0)
          val = sm.as[(23 + ((d - 35) >> 2)) * 132 + (r >> 2)];
        v[jj] = val;
      }
      *reinterpret_cast<fvec4*>(out + obase + 4 * z) = v;
    }
  }
}

extern "C" void kernel_launch(void* const* d_in, const int* in_sizes, int n_in,
                              void* d_out, int out_size, void* d_ws, size_t ws_size,
                              hipStream_t stream)
{
  const float* x  = (const float*)d_in[0];
  const float* w2 = (const float*)d_in[1];
  const float* b2 = (const float*)d_in[2];
  const float* w3 = (const float*)d_in[3];
  const float* b3 = (const float*)d_in[4];
  float* out = (float*)d_out;
  unsigned short* ws = (unsigned short*)d_ws;
  float* Y = (float*)((char*)d_ws + Y_OFF_B);
  unsigned* bar = (unsigned*)((char*)d_ws + BAR_OFF_B);

  mega_kernel<<<dim3(256), dim3(256), 0, stream>>>(x, w2, b2, w3, b3, out, ws, Y, bar);
}

// Round 6
// 855.876 us; speedup vs baseline: 1.4435x; 1.4435x over previous
//
#include <hip/hip_runtime.h>

// ---- types ----
typedef __bf16 bf16x8 __attribute__((ext_vector_type(8)));
typedef float  floatx4 __attribute__((ext_vector_type(4)));
typedef float  fvec4  __attribute__((ext_vector_type(4)));
typedef unsigned short ushort4v __attribute__((ext_vector_type(4)));
typedef unsigned short ushort8v __attribute__((ext_vector_type(8)));

__device__ __forceinline__ unsigned short f2bf(float f) {
  unsigned int u = __float_as_uint(f);
  u = u + 0x7FFFu + ((u >> 16) & 1u);   // RNE
  return (unsigned short)(u >> 16);
}

// ws layout (ushort elems unless noted):
//   WP2 @0 (29*256*512=3801088), WP3 @3801088 (2*256*768=393216),
//   X0 @4194304 [16*256][128], G0OUT @4718592 [16*256][120],
//   G1OUT @5210112 [16*256][56], G2OUT @5439488 [16*256][32] (scratch),
//   byte 64MiB: Y fp32 [31][16*256][128] compact stripe values.
#define WP3_OFF   3801088
#define X0_OFF    4194304
#define G0OUT_OFF 4718592
#define G1OUT_OFF 5210112
#define G2OUT_OFF 5439488
#define Y_OFF_B   (64u << 20)

// ---- prep: fp32 -> bf16 copies (w2, w3, x0). [o][i][k] == MFMA-B row order. ----
__global__ __launch_bounds__(256) void prep_kernel(
    const float* __restrict__ w2, const float* __restrict__ w3,
    const float* __restrict__ x, unsigned short* __restrict__ ws)
{
  int g = blockIdx.x * 256 + threadIdx.x;
  const float* src; unsigned short* dst;
  if (g < 950272)            { src = w2; dst = ws; }
  else if (g < 950272+98304) { g -= 950272; src = w3; dst = ws + WP3_OFF; }
  else                       { g -= (950272+98304); src = x; dst = ws + X0_OFF; }
  fvec4 v = *reinterpret_cast<const fvec4*>(src + 4*g);
  ushort4v o;
  o[0] = f2bf(v[0]); o[1] = f2bf(v[1]); o[2] = f2bf(v[2]); o[3] = f2bf(v[3]);
  *reinterpret_cast<ushort4v*>(dst + 4*g) = o;
}

union SMem {
  unsigned short a2[32 * 520];   // k2 A-tile: [m][kappa=2i+k], pitch 520
  unsigned short a3[32 * 776];   // k3 A-tile: [m][kappa=3i+k], pitch 776 (49.7 KB)
};

// ---- one conv step: MFMA over the LDS A-tile, write next A in-place + guarded globals ----
template<int KW>
__device__ __forceinline__ void step_body(
    unsigned short* A, unsigned short* An,          // may alias (k2 in-place)
    const unsigned short* __restrict__ wp, const float* __restrict__ bp,
    float* __restrict__ yl, unsigned short* __restrict__ xo, int Lpout, int writeX,
    int b, int m0, int wave, int l15, int quad, int Lf, int wf)
{
  constexpr int P  = (KW == 2) ? 520 : 776;
  constexpr int KS = 256 * KW;
  constexpr int NK = KS / 32;
  const int kb = quad * 8;

  floatx4 acc[2][4];
#pragma unroll
  for (int mf = 0; mf < 2; ++mf)
#pragma unroll
    for (int nf = 0; nf < 4; ++nf) acc[mf][nf] = floatx4{0.f, 0.f, 0.f, 0.f};

#pragma unroll
  for (int kc = 0; kc < NK; ++kc) {
    int ko = kc * 32 + kb;
    bf16x8 a0 = *reinterpret_cast<const bf16x8*>(&A[l15 * P + ko]);
    bf16x8 a1 = *reinterpret_cast<const bf16x8*>(&A[(16 + l15) * P + ko]);
#pragma unroll
    for (int nf = 0; nf < 4; ++nf) {
      const unsigned short* wr = wp + (long)(wave * 64 + nf * 16 + l15) * KS + ko;
      bf16x8 bf = *reinterpret_cast<const bf16x8*>(wr);
      acc[0][nf] = __builtin_amdgcn_mfma_f32_16x16x32_bf16(a0, bf, acc[0][nf], 0, 0, 0);
      acc[1][nf] = __builtin_amdgcn_mfma_f32_16x16x32_bf16(a1, bf, acc[1][nf], 0, 0, 0);
    }
  }
  __syncthreads();                                   // all A reads complete

#pragma unroll
  for (int nf = 0; nf < 4; ++nf) {
    const int n = wave * 64 + nf * 16 + l15;
    const float bv = bp[n];
    float* yrow = yl + (b * 256 + n) * 128 + m0;
    unsigned short* xrow = xo + (b * 256 + n) * Lpout + m0;
#pragma unroll
    for (int mf = 0; mf < 2; ++mf) {
#pragma unroll
      for (int r = 0; r < 4; ++r) {
        const int mloc = mf * 16 + quad * 4 + r;
        float v = acc[mf][nf][r] + bv;
        unsigned short h = f2bf(v);
        An[mloc * 520 + 2 * n] = h;                  // next-step kappa=2n (k=0)
        if (mloc >= 1) An[(mloc - 1) * 520 + 2 * n + 1] = h;  // kappa=2n+1 (k=1)
        if (mloc < wf && m0 + mloc < Lf) {           // wf guard: halo is garbage!
          yrow[mloc] = v;
          if (writeX) xrow[mloc] = h;
        }
      }
    }
  }
  __syncthreads();                                   // next A published
}

// ---- fused group: staging + F chained conv steps, zero grid-wide syncs ----
template<int F, int K3>
__global__ __launch_bounds__(256) void fused_group_kernel(
    const unsigned short* __restrict__ Xin, int Lpin,
    unsigned short* __restrict__ Xout, int Lpout,
    const unsigned short* __restrict__ WP3p, const float* __restrict__ b3p,
    const unsigned short* __restrict__ WP2p, const float* __restrict__ b2p,
    float* __restrict__ Ybase, int L0)
{
  constexpr int MT = 16;
  constexpr int W0 = MT + F - 1;                 // first-layer valid output width
  __shared__ SMem sm;

  const int tid = threadIdx.x;
  const int b   = blockIdx.y;
  const int m0  = blockIdx.x * MT;               // final-layer tile origin
  const int wave = tid >> 6, lane = tid & 63, l15 = lane & 15, quad = lane >> 4;

  // ---- stage step-0 A tile from global (thread = channel; over-reads benign) ----
  if constexpr (K3) {
    const int i = tid;
    const unsigned short* rp = Xin + (b * 256 + i) * Lpin + 2 * m0;
    ushort8v xr[6];
#pragma unroll
    for (int v = 0; v < 6; ++v) xr[v] = *reinterpret_cast<const ushort8v*>(rp + 8 * v);
    const unsigned short* xs = reinterpret_cast<const unsigned short*>(xr);
#pragma unroll
    for (int m = 0; m < W0; ++m) {               // W0=23: taps x[2m..2m+2]
      sm.a3[m * 776 + 3 * i]     = xs[2 * m];
      sm.a3[m * 776 + 3 * i + 1] = xs[2 * m + 1];
      sm.a3[m * 776 + 3 * i + 2] = xs[2 * m + 2];
    }
  } else {
    const int i = tid;
    const unsigned short* rp = Xin + (b * 256 + i) * Lpin + m0;
    ushort8v xr[4];
#pragma unroll
    for (int v = 0; v < 4; ++v) xr[v] = *reinterpret_cast<const ushort8v*>(rp + 8 * v);
    const unsigned short* xs = reinterpret_cast<const unsigned short*>(xr);
#pragma unroll
    for (int m = 0; m < W0; ++m) {               // W0=30: pairs {x[m], x[m+1]}
      unsigned int pk = (unsigned int)xs[m] | ((unsigned int)xs[m + 1] << 16);
      *reinterpret_cast<unsigned int*>(&sm.a2[m * 520 + 2 * i]) = pk;
    }
  }
  __syncthreads();

  int f0 = 0;
  if constexpr (K3) {
    step_body<3>(sm.a3, sm.a2, WP3p, b3p, Ybase, Xout, Lpout, 0,
                 b, m0, wave, l15, quad, L0, W0);
    f0 = 1;
  }
  for (int f = f0; f < F; ++f) {
    const unsigned short* wp = WP2p + (long)(f - f0) * 131072;
    const float* bp = b2p + (f - f0) * 256;
    float* yl = Ybase + (long)f * 524288;
    step_body<2>(sm.a2, sm.a2, wp, bp, yl, Xout, Lpout, (f == F - 1) ? 1 : 0,
                 b, m0, wave, l15, quad, L0 - f, MT + (F - 1 - f));
  }
}

// ---- assemble: coalesced full-map write composing zeros/diag/stripes (round-3) ----
__global__ __launch_bounds__(256) void assemble_kernel(
    float* __restrict__ out, const float* __restrict__ x, const float* __restrict__ Y)
{
  const int f0 = blockIdx.x * 256 + threadIdx.x;   // 0 .. 524287
  const int c4 = f0 & 31, r = (f0 >> 5) & 127;
  const int bch0 = f0 >> 12;

  int addr[4];
  bool dg[4];
#pragma unroll
  for (int jj = 0; jj < 4; ++jj) {
    int c = 4 * c4 + jj;
    int d = c - r;
    dg[jj] = (d == 0);
    int a = -1;
    if (d >= 1 && d <= 15) {
      a = (d - 1) * 524288 + r;
    } else if (d >= 17 && d <= 31 && (d & 1) == 1 && (r & 1) == 0) {
      a = (15 + ((d - 17) >> 1)) * 524288 + (r >> 1);
    } else if (d >= 35 && d <= 63 && (d & 3) == 3 && (r & 3) == 0) {
      a = (23 + ((d - 35) >> 2)) * 524288 + (r >> 2);
    }
    addr[jj] = a;
  }

  for (int it = 0; it < 32; ++it) {
    int bch = bch0 + it * 128;
    fvec4 v = {0.f, 0.f, 0.f, 0.f};
    int boff = bch * 128;
#pragma unroll
    for (int jj = 0; jj < 4; ++jj) {
      if (dg[jj])             v[jj] = x[boff + r];
      else if (addr[jj] >= 0) v[jj] = Y[addr[jj] + boff];
    }
    *reinterpret_cast<fvec4*>(out + (long)4 * (f0 + it * 524288)) = v;
  }
}

extern "C" void kernel_launch(void* const* d_in, const int* in_sizes, int n_in,
                              void* d_out, int out_size, void* d_ws, size_t ws_size,
                              hipStream_t stream)
{
  const float* x  = (const float*)d_in[0];
  const float* w2 = (const float*)d_in[1];
  const float* b2 = (const float*)d_in[2];
  const float* w3 = (const float*)d_in[3];
  const float* b3 = (const float*)d_in[4];
  float* out = (float*)d_out;
  unsigned short* ws = (unsigned short*)d_ws;
  float* Y = (float*)((char*)d_ws + Y_OFF_B);

  prep_kernel<<<4608, 256, 0, stream>>>(w2, w3, x, ws);

  // group 0: 15 k2 layers, L 128 -> 113  (c2 0..14, lidx 0..14)
  fused_group_kernel<15, 0><<<dim3(8, 16), 256, 0, stream>>>(
      ws + X0_OFF, 128, ws + G0OUT_OFF, 120,
      nullptr, nullptr, ws, b2, Y, 127);

  // group 1: k3s2 + 7 k2, L 113 -> 56 -> 49  (c3 0, c2 15..21, lidx 15..22)
  fused_group_kernel<8, 1><<<dim3(4, 16), 256, 0, stream>>>(
      ws + G0OUT_OFF, 120, ws + G1OUT_OFF, 56,
      ws + WP3_OFF, b3, ws + (long)15 * 131072, b2 + 15 * 256,
      Y + (long)15 * 524288, 56);

  // group 2: k3s2 + 7 k2, L 49 -> 24 -> 17  (c3 1, c2 22..28, lidx 23..30)
  fused_group_kernel<8, 1><<<dim3(2, 16), 256, 0, stream>>>(
      ws + G1OUT_OFF, 56, ws + G2OUT_OFF, 32,
      ws + WP3_OFF + 196608, b3 + 256, ws + (long)22 * 131072, b2 + 22 * 256,
      Y + (long)23 * 524288, 24);

  assemble_kernel<<<2048, 256, 0, stream>>>(out, x, Y);
}

// Round 7
// 725.100 us; speedup vs baseline: 1.7039x; 1.1804x over previous
//
#include <hip/hip_runtime.h>

// ---- types ----
typedef __bf16 bf16x8 __attribute__((ext_vector_type(8)));
typedef float  floatx4 __attribute__((ext_vector_type(4)));
typedef float  fvec4  __attribute__((ext_vector_type(4)));
typedef unsigned short ushort4v __attribute__((ext_vector_type(4)));
typedef unsigned short ushort8v __attribute__((ext_vector_type(8)));

__device__ __forceinline__ unsigned short f2bf(float f) {
  unsigned int u = __float_as_uint(f);
  u = u + 0x7FFFu + ((u >> 16) & 1u);   // RNE
  return (unsigned short)(u >> 16);
}

// ws layout (ushort elems unless noted):
//   WP2 @0 (29*256*512=3801088), WP3 @3801088 (2*256*768=393216),
//   X0 @4194304 [16*256][128], G0OUT @4718592 [16*256][120],
//   G1OUT @5210112 [16*256][56], G2OUT @5439488 [16*256][32] (scratch),
//   byte 64MiB: Y fp32 [31][16*256][128] compact stripe values.
#define WP3_OFF   3801088
#define X0_OFF    4194304
#define G0OUT_OFF 4718592
#define G1OUT_OFF 5210112
#define G2OUT_OFF 5439488
#define Y_OFF_B   (64u << 20)

// ---- prep: fp32 -> bf16 copies (w2, w3, x0). [o][i][k] == MFMA-B row order. ----
__global__ __launch_bounds__(256) void prep_kernel(
    const float* __restrict__ w2, const float* __restrict__ w3,
    const float* __restrict__ x, unsigned short* __restrict__ ws)
{
  int g = blockIdx.x * 256 + threadIdx.x;
  const float* src; unsigned short* dst;
  if (g < 950272)            { src = w2; dst = ws; }
  else if (g < 950272+98304) { g -= 950272; src = w3; dst = ws + WP3_OFF; }
  else                       { g -= (950272+98304); src = x; dst = ws + X0_OFF; }
  fvec4 v = *reinterpret_cast<const fvec4*>(src + 4*g);
  ushort4v o;
  o[0] = f2bf(v[0]); o[1] = f2bf(v[1]); o[2] = f2bf(v[2]); o[3] = f2bf(v[3]);
  *reinterpret_cast<ushort4v*>(dst + 4*g) = o;
}

// ---- one conv step: batched B-prefetch into registers, then MFMA; write next A
// in-place + guarded global stores. Accumulation order over kc identical to R6. ----
template<int KW>
__device__ __forceinline__ void step_body(
    unsigned short* A, unsigned short* An,          // may alias (sync-separated)
    const unsigned short* __restrict__ wp, const float* __restrict__ bp,
    float* __restrict__ yl, unsigned short* __restrict__ xo, int Lpout, int writeX,
    int b, int m0, int wave, int l15, int quad, int Lf, int wf)
{
  constexpr int P  = (KW == 2) ? 520 : 776;
  constexpr int KS = 256 * KW;
  constexpr int NK = KS / 32;          // 16 (k2) or 24 (k3)
  constexpr int NB = NK / 8;           // batches of 8 k-chunks
  const int kb = quad * 8;

  const unsigned short* wb = wp + (long)(wave * 64 + l15) * KS + kb;

  floatx4 acc[2][4];
#pragma unroll
  for (int mf = 0; mf < 2; ++mf)
#pragma unroll
    for (int nf = 0; nf < 4; ++nf) acc[mf][nf] = floatx4{0.f, 0.f, 0.f, 0.f};

#pragma unroll
  for (int bb = 0; bb < NB; ++bb) {
    bf16x8 bu[8][4];                   // 128 VGPRs: one batch of B-fragments
#pragma unroll
    for (int kc = 0; kc < 8; ++kc)
#pragma unroll
      for (int nf = 0; nf < 4; ++nf)
        bu[kc][nf] = *reinterpret_cast<const bf16x8*>(
            wb + (long)nf * 16 * KS + (bb * 8 + kc) * 32);
#pragma unroll
    for (int kc = 0; kc < 8; ++kc) {
      int ko = (bb * 8 + kc) * 32 + kb;
      bf16x8 a0 = *reinterpret_cast<const bf16x8*>(&A[l15 * P + ko]);
      bf16x8 a1 = *reinterpret_cast<const bf16x8*>(&A[(16 + l15) * P + ko]);
#pragma unroll
      for (int nf = 0; nf < 4; ++nf) {
        acc[0][nf] = __builtin_amdgcn_mfma_f32_16x16x32_bf16(a0, bu[kc][nf], acc[0][nf], 0, 0, 0);
        acc[1][nf] = __builtin_amdgcn_mfma_f32_16x16x32_bf16(a1, bu[kc][nf], acc[1][nf], 0, 0, 0);
      }
    }
  }
  __syncthreads();                                   // all A reads complete

#pragma unroll
  for (int nf = 0; nf < 4; ++nf) {
    const int n = wave * 64 + nf * 16 + l15;
    const float bv = bp[n];
    float* yrow = yl + (b * 256 + n) * 128 + m0;
    unsigned short* xrow = xo + (b * 256 + n) * Lpout + m0;
#pragma unroll
    for (int mf = 0; mf < 2; ++mf) {
#pragma unroll
      for (int r = 0; r < 4; ++r) {
        const int mloc = mf * 16 + quad * 4 + r;
        float v = acc[mf][nf][r] + bv;
        unsigned short h = f2bf(v);
        An[mloc * 520 + 2 * n] = h;                  // next-step kappa=2n (k=0)
        if (mloc >= 1) An[(mloc - 1) * 520 + 2 * n + 1] = h;  // kappa=2n+1 (k=1)
        if (mloc < wf && m0 + mloc < Lf) {           // wf guard: halo is garbage!
          yrow[mloc] = v;
          if (writeX) xrow[mloc] = h;
        }
      }
    }
  }
  __syncthreads();                                   // next A published
}

// ---- fused group: staging + F chained conv steps, zero grid-wide syncs ----
template<int F, int K3>
__global__ __launch_bounds__(256, 2) void fused_group_kernel(
    const unsigned short* __restrict__ Xin, int Lpin,
    unsigned short* __restrict__ Xout, int Lpout,
    const unsigned short* __restrict__ WP3p, const float* __restrict__ b3p,
    const unsigned short* __restrict__ WP2p, const float* __restrict__ b2p,
    float* __restrict__ Ybase, int L0)
{
  constexpr int MT = 16;
  constexpr int W0 = MT + F - 1;                 // first-layer valid output width
  __shared__ unsigned short smbuf[K3 ? 32 * 776 : 32 * 520];

  const int tid = threadIdx.x;
  const int b   = blockIdx.y;
  const int m0  = blockIdx.x * MT;               // final-layer tile origin
  const int wave = tid >> 6, lane = tid & 63, l15 = lane & 15, quad = lane >> 4;

  // ---- stage step-0 A tile from global (thread = channel; over-reads benign) ----
  if constexpr (K3) {
    const int i = tid;
    const unsigned short* rp = Xin + (b * 256 + i) * Lpin + 2 * m0;
    ushort8v xr[6];
#pragma unroll
    for (int v = 0; v < 6; ++v) xr[v] = *reinterpret_cast<const ushort8v*>(rp + 8 * v);
    const unsigned short* xs = reinterpret_cast<const unsigned short*>(xr);
#pragma unroll
    for (int m = 0; m < W0; ++m) {               // W0=23: taps x[2m..2m+2]
      smbuf[m * 776 + 3 * i]     = xs[2 * m];
      smbuf[m * 776 + 3 * i + 1] = xs[2 * m + 1];
      smbuf[m * 776 + 3 * i + 2] = xs[2 * m + 2];
    }
  } else {
    const int i = tid;
    const unsigned short* rp = Xin + (b * 256 + i) * Lpin + m0;
    ushort8v xr[4];
#pragma unroll
    for (int v = 0; v < 4; ++v) xr[v] = *reinterpret_cast<const ushort8v*>(rp + 8 * v);
    const unsigned short* xs = reinterpret_cast<const unsigned short*>(xr);
#pragma unroll
    for (int m = 0; m < W0; ++m) {               // W0=30: pairs {x[m], x[m+1]}
      unsigned int pk = (unsigned int)xs[m] | ((unsigned int)xs[m + 1] << 16);
      *reinterpret_cast<unsigned int*>(&smbuf[m * 520 + 2 * i]) = pk;
    }
  }
  __syncthreads();

  int f0 = 0;
  if constexpr (K3) {
    step_body<3>(smbuf, smbuf, WP3p, b3p, Ybase, Xout, Lpout, 0,
                 b, m0, wave, l15, quad, L0, W0);
    f0 = 1;
  }
  for (int f = f0; f < F; ++f) {
    const unsigned short* wp = WP2p + (long)(f - f0) * 131072;
    const float* bp = b2p + (f - f0) * 256;
    float* yl = Ybase + (long)f * 524288;
    step_body<2>(smbuf, smbuf, wp, bp, yl, Xout, Lpout, (f == F - 1) ? 1 : 0,
                 b, m0, wave, l15, quad, L0 - f, MT + (F - 1 - f));
  }
}

// ---- assemble: coalesced full-map write composing zeros/diag/stripes ----
__global__ __launch_bounds__(256) void assemble_kernel(
    float* __restrict__ out, const float* __restrict__ x, const float* __restrict__ Y)
{
  const int f0 = blockIdx.x * 256 + threadIdx.x;   // 0 .. 524287
  const int c4 = f0 & 31, r = (f0 >> 5) & 127;
  const int bch0 = f0 >> 12;

  int addr[4];
  bool dg[4];
#pragma unroll
  for (int jj = 0; jj < 4; ++jj) {
    int c = 4 * c4 + jj;
    int d = c - r;
    dg[jj] = (d == 0);
    int a = -1;
    if (d >= 1 && d <= 15) {
      a = (d - 1) * 524288 + r;
    } else if (d >= 17 && d <= 31 && (d & 1) == 1 && (r & 1) == 0) {
      a = (15 + ((d - 17) >> 1)) * 524288 + (r >> 1);
    } else if (d >= 35 && d <= 63 && (d & 3) == 3 && (r & 3) == 0) {
      a = (23 + ((d - 35) >> 2)) * 524288 + (r >> 2);
    }
    addr[jj] = a;
  }

  for (int it = 0; it < 32; ++it) {
    int bch = bch0 + it * 128;
    fvec4 v = {0.f, 0.f, 0.f, 0.f};
    int boff = bch * 128;
#pragma unroll
    for (int jj = 0; jj < 4; ++jj) {
      if (dg[jj])             v[jj] = x[boff + r];
      else if (addr[jj] >= 0) v[jj] = Y[addr[jj] + boff];
    }
    *reinterpret_cast<fvec4*>(out + (long)4 * (f0 + it * 524288)) = v;
  }
}

extern "C" void kernel_launch(void* const* d_in, const int* in_sizes, int n_in,
                              void* d_out, int out_size, void* d_ws, size_t ws_size,
                              hipStream_t stream)
{
  const float* x  = (const float*)d_in[0];
  const float* w2 = (const float*)d_in[1];
  const float* b2 = (const float*)d_in[2];
  const float* w3 = (const float*)d_in[3];
  const float* b3 = (const float*)d_in[4];
  float* out = (float*)d_out;
  unsigned short* ws = (unsigned short*)d_ws;
  float* Y = (float*)((char*)d_ws + Y_OFF_B);

  prep_kernel<<<4608, 256, 0, stream>>>(w2, w3, x, ws);

  // group 0: 15 k2 layers, L 128 -> 113  (c2 0..14, lidx 0..14)
  fused_group_kernel<15, 0><<<dim3(8, 16), 256, 0, stream>>>(
      ws + X0_OFF, 128, ws + G0OUT_OFF, 120,
      nullptr, nullptr, ws, b2, Y, 127);

  // group 1: k3s2 + 7 k2, L 113 -> 56 -> 49  (c3 0, c2 15..21, lidx 15..22)
  fused_group_kernel<8, 1><<<dim3(4, 16), 256, 0, stream>>>(
      ws + G0OUT_OFF, 120, ws + G1OUT_OFF, 56,
      ws + WP3_OFF, b3, ws + (long)15 * 131072, b2 + 15 * 256,
      Y + (long)15 * 524288, 56);

  // group 2: k3s2 + 7 k2, L 49 -> 24 -> 17  (c3 1, c2 22..28, lidx 23..30)
  fused_group_kernel<8, 1><<<dim3(2, 16), 256, 0, stream>>>(
      ws + G1OUT_OFF, 56, ws + G2OUT_OFF, 32,
      ws + WP3_OFF + 196608, b3 + 256, ws + (long)22 * 131072, b2 + 22 * 256,
      Y + (long)23 * 524288, 24);

  assemble_kernel<<<2048, 256, 0, stream>>>(out, x, Y);
}